// Round 6
// baseline (236.115 us; speedup 1.0000x reference)
//
#include <hip/hip_runtime.h>
#include <hip/hip_bf16.h>

// BertSelfAttention B=4,S=1024,HID=1024,H=16,D=64,MAXP=1024 — Round 6.
// R4/R5 "failures" were a launcher typo: cvt_bf16(hidden) converted only
// 1M of 4M floats (batch 0) — b>=1 read 0xAA poison => zero-ish output,
// absmax == stub's 0.1396. R6 = R5 verbatim + correct cvt count (4096 blks,
// n4=1048576). attn: barrier-free main loop, wave-private Toeplitz Tb,
// S^T orientation, E^T via wave-private LDS, direct global K/PE/V frags.
// ws: Xbf/Vt[0,8M) Wt[8M,14M) Db[14M,14.25M) Qf[15M) Kf[23M) Vf[31M)

#define EPSV 1e-8f

typedef short bfrag __attribute__((ext_vector_type(8)));   // 8 bf16
typedef float cfrag __attribute__((ext_vector_type(16)));  // C/D 32x32

__device__ __forceinline__ short f2bf(float f) {
    __hip_bfloat16 h = __float2bfloat16(f);
    return *reinterpret_cast<short*>(&h);
}
__device__ __forceinline__ float bf2f(short s) {
    unsigned int u = ((unsigned int)(unsigned short)s) << 16;
    return __builtin_bit_cast(float, u);
}
__device__ __forceinline__ unsigned int pk2(short a, short b) {
    return (unsigned int)(unsigned short)a | ((unsigned int)(unsigned short)b << 16);
}

// ---------------------------------------------------------------------------
__global__ __launch_bounds__(256) void cvt_bf16(
    const float* __restrict__ src, short* __restrict__ dst, int n4)
{
    int i = blockIdx.x * 256 + threadIdx.x;
    if (i >= n4) return;
    float4 v = ((const float4*)src)[i];
    short4 o;
    o.x = f2bf(v.x); o.y = f2bf(v.y); o.z = f2bf(v.z); o.w = f2bf(v.w);
    ((short4*)dst)[i] = o;
}

// W [1024 k][1024 n] f32 -> Wt [z][1024 n][1024 k] bf16
__global__ __launch_bounds__(256) void cvt_w_t(
    const float* __restrict__ Wq, const float* __restrict__ Wk,
    const float* __restrict__ Wv, short* __restrict__ Wt)
{
    __shared__ float Tl[32][33];
    const float* W = (blockIdx.z == 0) ? Wq : ((blockIdx.z == 1) ? Wk : Wv);
    short* out = Wt + (size_t)blockIdx.z * 1024 * 1024;
    const int t = threadIdx.x;
    const int k0 = blockIdx.x * 32, n0 = blockIdx.y * 32;
    {
        int kl = t >> 3, nl4 = (t & 7) * 4;
        float4 v = *(const float4*)(W + (size_t)(k0 + kl) * 1024 + n0 + nl4);
        Tl[kl][nl4] = v.x; Tl[kl][nl4 + 1] = v.y;
        Tl[kl][nl4 + 2] = v.z; Tl[kl][nl4 + 3] = v.w;
    }
    __syncthreads();
    int nl = t >> 3, kl4 = (t & 7) * 4;
    short4 o;
    o.x = f2bf(Tl[kl4][nl]);     o.y = f2bf(Tl[kl4 + 1][nl]);
    o.z = f2bf(Tl[kl4 + 2][nl]); o.w = f2bf(Tl[kl4 + 3][nl]);
    *(short4*)(out + (size_t)(n0 + nl) * 1024 + k0 + kl4) = o;
}

// ---------------------------------------------------------------------------
// QKV GEMM (R3-verified): Xbf [4096,1024] x Wt -> [bh][s][d] bf16.
// 128x128 tile, BK=32, rows padded to 40 shorts.
__global__ __launch_bounds__(256) void qkv_mfma(
    const short* __restrict__ Xbf, const short* __restrict__ Wt,
    const float* __restrict__ bq, const float* __restrict__ bk,
    const float* __restrict__ bv,
    short* __restrict__ Qf, short* __restrict__ Kf, short* __restrict__ Vf)
{
    __shared__ short As[128 * 40];
    __shared__ short Bs[128 * 40];
    const int z = blockIdx.z;
    const short* W = Wt + (size_t)z * 1024 * 1024;
    const float* bias = (z == 0) ? bq : ((z == 1) ? bk : bv);
    short* out = (z == 0) ? Qf : ((z == 1) ? Kf : Vf);
    const float scale = (z == 0) ? 0.125f : 1.0f;   // fold 1/sqrt(D) into Q

    const int tid = threadIdx.x, lane = tid & 63, wid = tid >> 6;
    const int q2 = lane >> 5, l31 = lane & 31;
    const int wr = wid >> 1, wc = wid & 1;
    const int m0 = blockIdx.x * 128, n0 = blockIdx.y * 128;

    cfrag acc[2][2];
#pragma unroll
    for (int i = 0; i < 2; i++)
#pragma unroll
        for (int j = 0; j < 2; j++)
#pragma unroll
            for (int e = 0; e < 16; e++) acc[i][j][e] = 0.f;

    for (int k0 = 0; k0 < 1024; k0 += 32) {
        bfrag xa[2], wb[2];
#pragma unroll
        for (int p = 0; p < 2; p++) {
            const int chunk = p * 256 + tid;
            const int r = chunk >> 2, c8 = (chunk & 3) * 8;
            xa[p] = *(const bfrag*)(Xbf + (size_t)(m0 + r) * 1024 + k0 + c8);
            wb[p] = *(const bfrag*)(W + (size_t)(n0 + r) * 1024 + k0 + c8);
        }
        __syncthreads();
#pragma unroll
        for (int p = 0; p < 2; p++) {
            const int chunk = p * 256 + tid;
            const int r = chunk >> 2, c8 = (chunk & 3) * 8;
            *(bfrag*)&As[r * 40 + c8] = xa[p];
            *(bfrag*)&Bs[r * 40 + c8] = wb[p];
        }
        __syncthreads();
        bfrag a[2][2], b[2][2];
#pragma unroll
        for (int mt = 0; mt < 2; mt++) {
            const int m = wr * 64 + mt * 32 + l31;
#pragma unroll
            for (int kc = 0; kc < 2; kc++)
                a[mt][kc] = *(const bfrag*)&As[m * 40 + kc * 16 + q2 * 8];
        }
#pragma unroll
        for (int nt = 0; nt < 2; nt++) {
            const int n = wc * 64 + nt * 32 + l31;
#pragma unroll
            for (int kc = 0; kc < 2; kc++)
                b[nt][kc] = *(const bfrag*)&Bs[n * 40 + kc * 16 + q2 * 8];
        }
#pragma unroll
        for (int mt = 0; mt < 2; mt++)
#pragma unroll
            for (int nt = 0; nt < 2; nt++)
#pragma unroll
                for (int kc = 0; kc < 2; kc++)
                    acc[mt][nt] = __builtin_amdgcn_mfma_f32_32x32x16_bf16(
                        a[mt][kc], b[nt][kc], acc[mt][nt], 0, 0, 0);
    }

    // R3-verified epilogue: +bias, (Q: x0.125), cvt bf16, scatter to [bh][s][d]
#pragma unroll
    for (int nt = 0; nt < 2; nt++) {
        const int c = n0 + wc * 64 + nt * 32 + l31;    // channel
        const float bval = bias[c];
        const int h = c >> 6, d = c & 63;
#pragma unroll
        for (int mt = 0; mt < 2; mt++) {
#pragma unroll
            for (int reg = 0; reg < 16; reg++) {
                const int row = (reg & 3) + 8 * (reg >> 2) + 4 * q2;
                const int tok = m0 + wr * 64 + mt * 32 + row;
                const int bb = tok >> 10, s = tok & 1023;
                const float v = (acc[mt][nt][reg] + bval) * scale;
                out[((size_t)(bb * 16 + h) * 1024 + s) * 64 + d] = f2bf(v);
            }
        }
    }
}

// Vf [bh][1024 s][64 d] -> Vt [bh][64 d][1024 s]  (R3-verified)
__global__ __launch_bounds__(256) void transpose_v(
    const short* __restrict__ Vf, short* __restrict__ Vt)
{
    __shared__ short Tl[64 * 72];
    const int bh = blockIdx.y, s0 = blockIdx.x * 64, tid = threadIdx.x;
    const short* src = Vf + ((size_t)bh * 1024 + s0) * 64;
#pragma unroll
    for (int p = 0; p < 2; p++) {
        const int off = (p * 256 + tid) * 8;
        const int s = off >> 6, d0 = off & 63;
        *(bfrag*)&Tl[s * 72 + d0] = *(const bfrag*)(src + (size_t)s * 64 + d0);
    }
    __syncthreads();
    short* dst = Vt + (size_t)bh * 64 * 1024 + s0;
#pragma unroll
    for (int p = 0; p < 2; p++) {
        const int off = (p * 256 + tid) * 8;
        const int d = off >> 6, sl0 = off & 63;
        short tmp[8];
#pragma unroll
        for (int j = 0; j < 8; j++) tmp[j] = Tl[(sl0 + j) * 72 + d];
        *(bfrag*)(dst + (size_t)d * 1024 + sl0) = *(bfrag*)tmp;
    }
}

// ---------------------------------------------------------------------------
// Fused attention. grid (8 l-tiles of 128, 64 bh), 256 thr = 4 waves.
// Wave w owns l-cols [l0+32w, +32) for ALL r. No __syncthreads in main loop.
// E^T goes through wave-private LDS Es[w] (verified C->B transform).
__global__ __launch_bounds__(256) void attn_mfma(
    const short* __restrict__ Qf, const short* __restrict__ Kf,
    const short* __restrict__ Vt, const short* __restrict__ Db,
    const float* __restrict__ amask, const int* __restrict__ skim,
    float* __restrict__ out)
{
    __shared__ short Tb[128 * 132];   // rolling T[l_local][slot], pad 132
    __shared__ short Es[4][32 * 72];  // wave-private E^T staging, pad 72
    __shared__ float Lg[1024];        // g[r] = exp(amask)*skim

    const int tid = threadIdx.x, lane = tid & 63, w = tid >> 6;
    const int q2 = lane >> 5, l31 = lane & 31;
    const int h2 = w >> 1;            // l-half of this wave
    const int bh = blockIdx.y, b = bh >> 4, hh = bh & 15;
    const int l0 = blockIdx.x * 128;

    // stage g once
    {
        const int r4 = tid * 4;
        float4 am = *(const float4*)(amask + b * 1024 + r4);
        int4 sk = *(const int4*)(skim + b * 1024 + r4);
        Lg[r4 + 0] = __expf(am.x) * (float)sk.x;
        Lg[r4 + 1] = __expf(am.y) * (float)sk.y;
        Lg[r4 + 2] = __expf(am.z) * (float)sk.z;
        Lg[r4 + 3] = __expf(am.w) * (float)sk.w;
    }
    __syncthreads();

    // Q B-frags (pre-scaled by 1/8 in qkv): wave's l-col = l0 + 32w + l31
    bfrag qa[4];
    {
        const short* qrow = Qf + ((size_t)bh * 1024 + l0 + 32 * w + l31) * 64;
#pragma unroll
        for (int c = 0; c < 4; c++)
            qa[c] = *(const bfrag*)(qrow + c * 16 + q2 * 8);
    }
    const short* Kg = Kf + (size_t)bh * 1024 * 64;   // [s][d]
    const short* Vg = Vt + (size_t)bh * 64 * 1024;   // [d][s]

    cfrag oacc[2];
#pragma unroll
    for (int mt = 0; mt < 2; mt++)
#pragma unroll
        for (int e = 0; e < 16; e++) oacc[mt][e] = 0.f;
    float esum = 0.f;

    const int lrow = 32 * w + l31;    // Tb row (wave-private band)

    for (int r0 = -64; r0 < 1024; r0 += 64) {
        // ---- Toeplitz T^T for this wave's l-half: new 64-dist block ----
        const int bd = l0 - r0 - 64 + 64 * h2;
#pragma unroll
        for (int mt = 0; mt < 2; mt++) {
            cfrag t;
#pragma unroll
            for (int e = 0; e < 16; e++) t[e] = 0.f;
            const int drow = bd + 32 * mt + l31;
            const int er = min(max(drow + 1023, 0), 2046);
#pragma unroll
            for (int kc = 0; kc < 4; kc++) {
                bfrag pb = *(const bfrag*)(Db + (size_t)er * 64 + kc * 16 + q2 * 8);
                t = __builtin_amdgcn_mfma_f32_32x32x16_bf16(pb, qa[kc], t, 0, 0, 0);
            }
#pragma unroll
            for (int g = 0; g < 4; g++) {
                const int slot = (bd + 32 * mt + 8 * g + 4 * q2) & 127;
                uint2 w2;
                w2.x = pk2(f2bf(t[4 * g + 0]), f2bf(t[4 * g + 1]));
                w2.y = pk2(f2bf(t[4 * g + 2]), f2bf(t[4 * g + 3]));
                *(uint2*)&Tb[lrow * 132 + slot] = w2;
            }
        }
        if (r0 < 0) continue;

        // ---- scores S^T = K . Q^T (A=K direct from global) ----
        cfrag sfr[2];
#pragma unroll
        for (int mt = 0; mt < 2; mt++) {
#pragma unroll
            for (int e = 0; e < 16; e++) sfr[mt][e] = 0.f;
            const short* krow = Kg + (size_t)(r0 + 32 * mt + l31) * 64;
#pragma unroll
            for (int kc = 0; kc < 4; kc++) {
                bfrag kb = *(const bfrag*)(krow + kc * 16 + q2 * 8);
                sfr[mt] = __builtin_amdgcn_mfma_f32_32x32x16_bf16(
                    kb, qa[kc], sfr[mt], 0, 0, 0);
            }
        }

        // ---- masked-softmax numerators -> wave-private Es (E^T layout) ----
        const int lg = l0 + 32 * w + l31;       // this lane's l
#pragma unroll
        for (int mt = 0; mt < 2; mt++) {
#pragma unroll
            for (int g = 0; g < 4; g++) {
                const int rb = r0 + 32 * mt + 8 * g + 4 * q2;
                float4 g4 = *(const float4*)&Lg[rb];
                short s4[4];
#pragma unroll
                for (int j = 0; j < 4; j++) {
                    const int dist = lg - (rb + j);
                    const float tv = bf2f(Tb[lrow * 132 + (dist & 127)]);
                    const float gv = (j == 0) ? g4.x : (j == 1) ? g4.y
                                   : (j == 2) ? g4.z : g4.w;
                    const float e = __expf(sfr[mt][4 * g + j] + tv) * gv;
                    s4[j] = f2bf(e);
                    esum += bf2f(s4[j]);
                }
                uint2 w2;
                w2.x = pk2(s4[0], s4[1]);
                w2.y = pk2(s4[2], s4[3]);
                // E^T[r-local][l-local l31]: row l31, col = 32mt+8g+4q2
                *(uint2*)&Es[w][l31 * 72 + 32 * mt + 8 * g + 4 * q2] = w2;
            }
        }

        // ---- PV: O^T = V^T . E^T ; B-frag read back from private Es ----
#pragma unroll
        for (int kc = 0; kc < 4; kc++) {
            bfrag ef = *(const bfrag*)&Es[w][l31 * 72 + kc * 16 + q2 * 8];
#pragma unroll
            for (int mtd = 0; mtd < 2; mtd++) {
                bfrag vb = *(const bfrag*)(Vg + (size_t)(32 * mtd + l31) * 1024
                                           + r0 + kc * 16 + q2 * 8);
                oacc[mtd] = __builtin_amdgcn_mfma_f32_32x32x16_bf16(
                    vb, ef, oacc[mtd], 0, 0, 0);
            }
        }
    }

    // ---- finalize: denom per l (lane), coalesced float4 stores ----
    const float den = EPSV + esum + __shfl_xor(esum, 32);
    const float inv = 1.0f / den;
    const int lg = l0 + 32 * w + l31;
    float* ob = out + ((size_t)(b * 1024 + lg) * 1024) + hh * 64;
#pragma unroll
    for (int mtd = 0; mtd < 2; mtd++) {
#pragma unroll
        for (int g = 0; g < 4; g++) {
            float4 o;
            o.x = oacc[mtd][4 * g + 0] * inv;
            o.y = oacc[mtd][4 * g + 1] * inv;
            o.z = oacc[mtd][4 * g + 2] * inv;
            o.w = oacc[mtd][4 * g + 3] * inv;
            *(float4*)(ob + 32 * mtd + 8 * g + 4 * q2) = o;
        }
    }
}

// ---------------------------------------------------------------------------
extern "C" void kernel_launch(void* const* d_in, const int* in_sizes, int n_in,
                              void* d_out, int out_size, void* d_ws, size_t ws_size,
                              hipStream_t stream) {
    const float* hidden = (const float*)d_in[0];
    const float* amask  = (const float*)d_in[1];
    const int*   skim   = (const int*)d_in[2];
    const float* Wq     = (const float*)d_in[3];
    const float* bq     = (const float*)d_in[4];
    const float* Wk     = (const float*)d_in[5];
    const float* bk     = (const float*)d_in[6];
    const float* Wv     = (const float*)d_in[7];
    const float* bv     = (const float*)d_in[8];
    const float* dist   = (const float*)d_in[9];
    float* out = (float*)d_out;

    char* w = (char*)d_ws;
    short* Xbf = (short*)(w);                        // 8 MB (reused as Vt)
    short* Wt  = (short*)(w + ((size_t)8 << 20));    // 6 MB
    short* Db  = (short*)(w + ((size_t)14 << 20));   // 0.25 MB
    short* Qf  = (short*)(w + ((size_t)15 << 20));   // 8 MB
    short* Kf  = (short*)(w + ((size_t)23 << 20));   // 8 MB
    short* Vf  = (short*)(w + ((size_t)31 << 20));   // 8 MB
    short* Vt  = Xbf;                                // Xbf dead after qkv_mfma

    // hidden: 4*1024*1024 = 4,194,304 floats = 1,048,576 float4 chunks
    cvt_bf16<<<4096, 256, 0, stream>>>(hidden, Xbf, 1048576);
    cvt_bf16<<<128, 256, 0, stream>>>(dist, Db, 32752);
    cvt_w_t<<<dim3(32, 32, 3), 256, 0, stream>>>(Wq, Wk, Wv, Wt);
    qkv_mfma<<<dim3(32, 8, 3), 256, 0, stream>>>(Xbf, Wt, bq, bk, bv, Qf, Kf, Vf);
    transpose_v<<<dim3(16, 64), 256, 0, stream>>>(Vf, Vt);
    attn_mfma<<<dim3(8, 64), 256, 0, stream>>>(Qf, Kf, Vt, Db, amask, skim, out);
}

// Round 7
// 199.296 us; speedup vs baseline: 1.1847x; 1.1847x over previous
//
#include <hip/hip_runtime.h>
#include <hip/hip_bf16.h>

// BertSelfAttention B=4,S=1024,HID=1024,H=16,D=64,MAXP=1024 — Round 7.
// R6 post-mortem: attn frag loads from global were 128B-stride scattered
// (16/128 bytes used per line), latency-bound at 2 blocks/CU. R7: fragment-
// major layouts everywhere: chunk ((t32*nk + kc)*64 + lane)*8 so every MFMA
// A/B-frag load is one contiguous 1KB wave load. qkv goes LDS-free (stream
// from L2), V^T swizzle written directly (transpose_v deleted), prep fused
// into one kernel (3 launches total). attn grid (bh,lt) for XCD L2 locality.
// ws: Xs[0,8M) Wt[8M,14M) Db[14M,14.25M) Qf[15M) Kf[23M) Vt[31M)

#define EPSV 1e-8f

typedef short bfrag __attribute__((ext_vector_type(8)));   // 8 bf16
typedef float cfrag __attribute__((ext_vector_type(16)));  // C/D 32x32

__device__ __forceinline__ short f2bf(float f) {
    __hip_bfloat16 h = __float2bfloat16(f);
    return *reinterpret_cast<short*>(&h);
}
__device__ __forceinline__ float bf2f(short s) {
    unsigned int u = ((unsigned int)(unsigned short)s) << 16;
    return __builtin_bit_cast(float, u);
}
__device__ __forceinline__ unsigned int pk2(short a, short b) {
    return (unsigned int)(unsigned short)a | ((unsigned int)(unsigned short)b << 16);
}

// ---------------------------------------------------------------------------
// prep: fused cvt/swizzle. grid.x = 3648, 256 thr.
//  [0,2048): hidden -> Xs frag-major [4096 m][1024 k]
//  [2048,3584): Wq/Wk/Wv [k][n] -> Wt frag-major [1024 n][1024 k] (transpose)
//  [3584,3648): dist -> Db bf16 row-major [2047][64]
__global__ __launch_bounds__(256) void prep(
    const float* __restrict__ hidden, const float* __restrict__ Wq,
    const float* __restrict__ Wk, const float* __restrict__ Wv,
    const float* __restrict__ dist,
    short* __restrict__ Xs, short* __restrict__ Wt, short* __restrict__ Db)
{
    __shared__ short Tl[32 * 72];
    const int bid = blockIdx.x, tid = threadIdx.x;

    if (bid < 2048) {                      // X: 128 m-tiles x 16 k-groups
        const int mt = bid >> 4, kg = bid & 15;
        const int m_l = tid >> 3, k8 = (tid & 7) * 8;
        const float* src = hidden + (size_t)(mt * 32 + m_l) * 1024 + kg * 64 + k8;
        float4 v0 = *(const float4*)src, v1 = *(const float4*)(src + 4);
        short o[8];
        o[0] = f2bf(v0.x); o[1] = f2bf(v0.y); o[2] = f2bf(v0.z); o[3] = f2bf(v0.w);
        o[4] = f2bf(v1.x); o[5] = f2bf(v1.y); o[6] = f2bf(v1.z); o[7] = f2bf(v1.w);
        *(bfrag*)&Tl[m_l * 72 + k8] = *(bfrag*)o;
        __syncthreads();
        const int l31 = tid & 31, q2 = (tid >> 5) & 1, kc = tid >> 6;
        bfrag r = *(const bfrag*)&Tl[l31 * 72 + kc * 16 + q2 * 8];
        *(bfrag*)(Xs + ((size_t)(mt * 64 + kg * 4 + kc) * 64 + q2 * 32 + l31) * 8) = r;
    } else if (bid < 3584) {               // W: 3 z x 32 n-tiles x 16 k-groups
        const int t = bid - 2048, z = t >> 9, nt = (t >> 4) & 31, kg = t & 15;
        const float* W = (z == 0) ? Wq : ((z == 1) ? Wk : Wv);
        const int k_l = tid >> 2, n8 = (tid & 3) * 8;
        const float* src = W + (size_t)(kg * 64 + k_l) * 1024 + nt * 32 + n8;
        float4 v0 = *(const float4*)src, v1 = *(const float4*)(src + 4);
        float vv[8] = {v0.x, v0.y, v0.z, v0.w, v1.x, v1.y, v1.z, v1.w};
#pragma unroll
        for (int i = 0; i < 8; i++)
            Tl[(n8 + i) * 72 + k_l] = f2bf(vv[i]);   // transpose into LDS
        __syncthreads();
        const int l31 = tid & 31, q2 = (tid >> 5) & 1, kc = tid >> 6;
        bfrag r = *(const bfrag*)&Tl[l31 * 72 + kc * 16 + q2 * 8];
        *(bfrag*)(Wt + (size_t)z * 1048576
                  + ((size_t)(nt * 64 + kg * 4 + kc) * 64 + q2 * 32 + l31) * 8) = r;
    } else {                               // dist: 2047*64 = 131008 elems
        const int idx = (bid - 3584) * 256 + tid;
        if (idx < 16376) {
            const float* src = dist + (size_t)idx * 8;
            float4 v0 = *(const float4*)src, v1 = *(const float4*)(src + 4);
            short o[8];
            o[0] = f2bf(v0.x); o[1] = f2bf(v0.y); o[2] = f2bf(v0.z); o[3] = f2bf(v0.w);
            o[4] = f2bf(v1.x); o[5] = f2bf(v1.y); o[6] = f2bf(v1.z); o[7] = f2bf(v1.w);
            *(bfrag*)(Db + (size_t)idx * 8) = *(bfrag*)o;
        }
    }
}

// ---------------------------------------------------------------------------
// QKV GEMM, LDS-free: Xs/Wt frag-major in, Qf/Kf frag-major [s][d] per bh,
// Vt frag-major over V^T [d][s] per bh. 128x128 block, 4 waves 2x2 of 64x64.
__global__ __launch_bounds__(256) void qkv_mfma(
    const short* __restrict__ Xs, const short* __restrict__ Wt,
    const float* __restrict__ bq, const float* __restrict__ bk,
    const float* __restrict__ bv,
    short* __restrict__ Qf, short* __restrict__ Kf, short* __restrict__ Vt)
{
    const int z = blockIdx.z;
    const short* W = Wt + (size_t)z * 1048576;
    const float* bias = (z == 0) ? bq : ((z == 1) ? bk : bv);
    const float scale = (z == 0) ? 0.125f : 1.0f;   // fold 1/sqrt(D) into Q

    const int tid = threadIdx.x, lane = tid & 63, wid = tid >> 6;
    const int q2 = lane >> 5, l31 = lane & 31;
    const int wr = wid >> 1, wc = wid & 1;
    const int m0 = blockIdx.x * 128, n0 = blockIdx.y * 128;

    cfrag acc[2][2];
#pragma unroll
    for (int i = 0; i < 2; i++)
#pragma unroll
        for (int j = 0; j < 2; j++)
#pragma unroll
            for (int e = 0; e < 16; e++) acc[i][j][e] = 0.f;

    const short* ap0 = Xs + ((size_t)((m0 >> 5) + wr * 2 + 0) * 64 * 64 + lane) * 8;
    const short* ap1 = Xs + ((size_t)((m0 >> 5) + wr * 2 + 1) * 64 * 64 + lane) * 8;
    const short* bp0 = W  + ((size_t)((n0 >> 5) + wc * 2 + 0) * 64 * 64 + lane) * 8;
    const short* bp1 = W  + ((size_t)((n0 >> 5) + wc * 2 + 1) * 64 * 64 + lane) * 8;

#pragma unroll 4
    for (int kc = 0; kc < 64; kc++) {
        const int off = kc * 512;          // 64 chunks * 8 shorts
        bfrag a0 = *(const bfrag*)(ap0 + off);
        bfrag a1 = *(const bfrag*)(ap1 + off);
        bfrag b0 = *(const bfrag*)(bp0 + off);
        bfrag b1 = *(const bfrag*)(bp1 + off);
        acc[0][0] = __builtin_amdgcn_mfma_f32_32x32x16_bf16(a0, b0, acc[0][0], 0, 0, 0);
        acc[0][1] = __builtin_amdgcn_mfma_f32_32x32x16_bf16(a0, b1, acc[0][1], 0, 0, 0);
        acc[1][0] = __builtin_amdgcn_mfma_f32_32x32x16_bf16(a1, b0, acc[1][0], 0, 0, 0);
        acc[1][1] = __builtin_amdgcn_mfma_f32_32x32x16_bf16(a1, b1, acc[1][1], 0, 0, 0);
    }

    // epilogue: +bias, (Q: x0.125), cvt bf16, scatter frag-major per bh
#pragma unroll
    for (int nt = 0; nt < 2; nt++) {
        const int c = n0 + wc * 64 + nt * 32 + l31;    // channel
        const float bval = bias[c];
        const int h = c >> 6;
        const int d = nt * 32 + l31;                   // c & 63
#pragma unroll
        for (int mt = 0; mt < 2; mt++) {
            const int tok0 = m0 + wr * 64 + mt * 32;
            const int bb = tok0 >> 10, s_base = tok0 & 1023;
            const size_t bhbase = (size_t)(bb * 16 + h) * 65536;
            if (z < 2) {
                short* outp = (z == 0) ? Qf : Kf;
                const size_t fbase = bhbase
                    + ((size_t)((s_base >> 5) * 4 + (d >> 4)) * 64
                       + ((d >> 3) & 1) * 32) * 8 + (d & 7);
#pragma unroll
                for (int reg = 0; reg < 16; reg++) {
                    const int row = (reg & 3) + 8 * (reg >> 2) + 4 * q2;
                    outp[fbase + (size_t)row * 8] = f2bf((acc[mt][nt][reg] + bval) * scale);
                }
            } else {
                // V^T frag-major: elem (d, s): ((d>>5)*64 + (s>>4))*64*8 ...
#pragma unroll
                for (int g = 0; g < 4; g++) {
                    const float e0 = acc[mt][nt][4 * g + 0] + bval;
                    const float e1 = acc[mt][nt][4 * g + 1] + bval;
                    const float e2 = acc[mt][nt][4 * g + 2] + bval;
                    const float e3 = acc[mt][nt][4 * g + 3] + bval;
                    uint2 w2;
                    w2.x = pk2(f2bf(e0), f2bf(e1));
                    w2.y = pk2(f2bf(e2), f2bf(e3));
                    const size_t flat = bhbase
                        + ((size_t)(nt * 64 + (s_base >> 4) + (g >> 1)) * 64
                           + (g & 1) * 32 + l31) * 8 + 4 * q2;
                    *(uint2*)(Vt + flat) = w2;
                }
            }
        }
    }
}

// ---------------------------------------------------------------------------
// Fused attention. grid (64 bh = x, 8 l-tiles = y) -> 8 l-blocks of one bh
// share an XCD (d%8 heuristic). 4 waves; wave w owns l-cols [l0+32w,+32) for
// all r. Barrier-free main loop; all K/V/Q frag loads coalesced 1KB.
__global__ __launch_bounds__(256) void attn_mfma(
    const short* __restrict__ Qf, const short* __restrict__ Kf,
    const short* __restrict__ Vt, const short* __restrict__ Db,
    const float* __restrict__ amask, const int* __restrict__ skim,
    float* __restrict__ out)
{
    __shared__ short Tb[128 * 132];   // rolling T[l_local][slot]
    __shared__ short Es[4][32 * 72];  // wave-private E^T staging
    __shared__ float Lg[1024];        // g[r] = exp(amask)*skim

    const int tid = threadIdx.x, lane = tid & 63, w = tid >> 6;
    const int q2 = lane >> 5, l31 = lane & 31;
    const int h2 = w >> 1;
    const int bh = blockIdx.x, b = bh >> 4, hh = bh & 15;
    const int l0 = blockIdx.y * 128;

    {
        const int r4 = tid * 4;
        float4 am = *(const float4*)(amask + b * 1024 + r4);
        int4 sk = *(const int4*)(skim + b * 1024 + r4);
        Lg[r4 + 0] = __expf(am.x) * (float)sk.x;
        Lg[r4 + 1] = __expf(am.y) * (float)sk.y;
        Lg[r4 + 2] = __expf(am.z) * (float)sk.z;
        Lg[r4 + 3] = __expf(am.w) * (float)sk.w;
    }
    __syncthreads();

    const short* Qg = Qf + (size_t)bh * 65536;
    const short* Kg = Kf + (size_t)bh * 65536;
    const short* Vg = Vt + (size_t)bh * 65536;

    // Q B-frags (pre-scaled by 1/8): chunk (( (l0>>5)+w )*4 + c)*64 + lane
    bfrag qa[4];
#pragma unroll
    for (int c = 0; c < 4; c++)
        qa[c] = *(const bfrag*)(Qg + ((size_t)(((l0 >> 5) + w) * 4 + c) * 64 + lane) * 8);

    cfrag oacc[2];
#pragma unroll
    for (int mt = 0; mt < 2; mt++)
#pragma unroll
        for (int e = 0; e < 16; e++) oacc[mt][e] = 0.f;
    float esum = 0.f;

    const int lrow = 32 * w + l31;    // Tb row (wave-private band)

    for (int r0 = -64; r0 < 1024; r0 += 64) {
        // ---- Toeplitz T^T: new 64-dist block for this wave's l-half ----
        const int bd = l0 - r0 - 64 + 64 * h2;
#pragma unroll
        for (int mt = 0; mt < 2; mt++) {
            cfrag t;
#pragma unroll
            for (int e = 0; e < 16; e++) t[e] = 0.f;
            const int drow = bd + 32 * mt + l31;
            const int er = min(max(drow + 1023, 0), 2046);
#pragma unroll
            for (int kc = 0; kc < 4; kc++) {
                bfrag pb = *(const bfrag*)(Db + (size_t)er * 64 + kc * 16 + q2 * 8);
                t = __builtin_amdgcn_mfma_f32_32x32x16_bf16(pb, qa[kc], t, 0, 0, 0);
            }
#pragma unroll
            for (int g = 0; g < 4; g++) {
                const int slot = (bd + 32 * mt + 8 * g + 4 * q2) & 127;
                uint2 w2;
                w2.x = pk2(f2bf(t[4 * g + 0]), f2bf(t[4 * g + 1]));
                w2.y = pk2(f2bf(t[4 * g + 2]), f2bf(t[4 * g + 3]));
                *(uint2*)&Tb[lrow * 132 + slot] = w2;
            }
        }
        if (r0 < 0) continue;

        // ---- scores S^T = K . Q^T, K A-frags coalesced ----
        cfrag sfr[2];
#pragma unroll
        for (int mt = 0; mt < 2; mt++) {
#pragma unroll
            for (int e = 0; e < 16; e++) sfr[mt][e] = 0.f;
#pragma unroll
            for (int kc = 0; kc < 4; kc++) {
                bfrag kb = *(const bfrag*)(Kg
                    + ((size_t)(((r0 >> 5) + mt) * 4 + kc) * 64 + lane) * 8);
                sfr[mt] = __builtin_amdgcn_mfma_f32_32x32x16_bf16(
                    kb, qa[kc], sfr[mt], 0, 0, 0);
            }
        }

        // ---- masked-softmax numerators -> wave-private Es (E^T layout) ----
        const int lg = l0 + 32 * w + l31;
#pragma unroll
        for (int mt = 0; mt < 2; mt++) {
#pragma unroll
            for (int g = 0; g < 4; g++) {
                const int rb = r0 + 32 * mt + 8 * g + 4 * q2;
                float4 g4 = *(const float4*)&Lg[rb];
                short s4[4];
#pragma unroll
                for (int j = 0; j < 4; j++) {
                    const int dist = lg - (rb + j);
                    const float tv = bf2f(Tb[lrow * 132 + (dist & 127)]);
                    const float gv = (j == 0) ? g4.x : (j == 1) ? g4.y
                                   : (j == 2) ? g4.z : g4.w;
                    const float e = __expf(sfr[mt][4 * g + j] + tv) * gv;
                    s4[j] = f2bf(e);
                    esum += bf2f(s4[j]);
                }
                uint2 w2;
                w2.x = pk2(s4[0], s4[1]);
                w2.y = pk2(s4[2], s4[3]);
                *(uint2*)&Es[w][l31 * 72 + 32 * mt + 8 * g + 4 * q2] = w2;
            }
        }

        // ---- PV: O^T = V^T . E^T ; V^T A-frags coalesced ----
#pragma unroll
        for (int kc = 0; kc < 4; kc++) {
            bfrag ef = *(const bfrag*)&Es[w][l31 * 72 + kc * 16 + q2 * 8];
#pragma unroll
            for (int mtd = 0; mtd < 2; mtd++) {
                bfrag vb = *(const bfrag*)(Vg
                    + ((size_t)(mtd * 64 + (r0 >> 4) + kc) * 64 + lane) * 8);
                oacc[mtd] = __builtin_amdgcn_mfma_f32_32x32x16_bf16(
                    vb, ef, oacc[mtd], 0, 0, 0);
            }
        }
    }

    // ---- finalize ----
    const float den = EPSV + esum + __shfl_xor(esum, 32);
    const float inv = 1.0f / den;
    const int lg = l0 + 32 * w + l31;
    float* ob = out + ((size_t)(b * 1024 + lg) * 1024) + hh * 64;
#pragma unroll
    for (int mtd = 0; mtd < 2; mtd++) {
#pragma unroll
        for (int g = 0; g < 4; g++) {
            float4 o;
            o.x = oacc[mtd][4 * g + 0] * inv;
            o.y = oacc[mtd][4 * g + 1] * inv;
            o.z = oacc[mtd][4 * g + 2] * inv;
            o.w = oacc[mtd][4 * g + 3] * inv;
            *(float4*)(ob + 32 * mtd + 8 * g + 4 * q2) = o;
        }
    }
}

// ---------------------------------------------------------------------------
extern "C" void kernel_launch(void* const* d_in, const int* in_sizes, int n_in,
                              void* d_out, int out_size, void* d_ws, size_t ws_size,
                              hipStream_t stream) {
    const float* hidden = (const float*)d_in[0];
    const float* amask  = (const float*)d_in[1];
    const int*   skim   = (const int*)d_in[2];
    const float* Wq     = (const float*)d_in[3];
    const float* bq     = (const float*)d_in[4];
    const float* Wk     = (const float*)d_in[5];
    const float* bk     = (const float*)d_in[6];
    const float* Wv     = (const float*)d_in[7];
    const float* bv     = (const float*)d_in[8];
    const float* dist   = (const float*)d_in[9];
    float* out = (float*)d_out;

    char* w = (char*)d_ws;
    short* Xs  = (short*)(w);                        // 8 MB frag-major X
    short* Wt  = (short*)(w + ((size_t)8 << 20));    // 6 MB frag-major W^T
    short* Db  = (short*)(w + ((size_t)14 << 20));   // 0.25 MB dist bf16
    short* Qf  = (short*)(w + ((size_t)15 << 20));   // 8 MB frag-major Q
    short* Kf  = (short*)(w + ((size_t)23 << 20));   // 8 MB frag-major K
    short* Vt  = (short*)(w + ((size_t)31 << 20));   // 8 MB frag-major V^T

    prep<<<3648, 256, 0, stream>>>(hidden, Wq, Wk, Wv, dist, Xs, Wt, Db);
    qkv_mfma<<<dim3(32, 8, 3), 256, 0, stream>>>(Xs, Wt, bq, bk, bv, Qf, Kf, Vt);
    attn_mfma<<<dim3(64, 8), 256, 0, stream>>>(Qf, Kf, Vt, Db, amask, skim, out);
}